// Round 8
// baseline (137.933 us; speedup 1.0000x reference)
//
#include <hip/hip_runtime.h>

// ConvTranspose3d (2,64,32^3) fp32 -> (2,32,66^3), stride2 pad1 outpad1 dil2 k3.
// Odd-grid MFMA: out[n,co,2dp+1,2hp+1,2wp+1] = bias[co] +
//   sum_{ci,kd,kh,kw} x[n,ci,dp+1-kd,hp+1-kh,wp+1-kw] * w[ci,co,kd,kh,kw]
// R8: im2col-from-global. Pre-pass makes x16[n][id][ih][iwl(34)][ci(64)] f16
// (iw halo zero-padded), so every MFMA B-fragment is ONE coalesced
// global_load_dwordx4 (L1/L2-served). No x staging, no K-loop barriers.
// Waves are split-K pairs (ci halves), combined via 16 KB LDS reduction.

#define DOUT 66
#define PL (DOUT*DOUT)                   // 4356 floats/plane

typedef _Float16 half8 __attribute__((ext_vector_type(8)));
typedef float    floatx16 __attribute__((ext_vector_type(16)));

#define X16_N_STRIDE  2228224            // 32*32*34*64 f16
#define X16_ROW       2176               // 34*64 f16
#define WT_BYTES      110592
#define X16_OFF       131072             // byte offset of x16 in d_ws

// ---- k0: w (64,32,3,3,3) f32 -> wT[tap(27)][co(32)][ci(64)] f16 ----
__global__ void w_transpose(const float* __restrict__ w, _Float16* __restrict__ wT) {
    int o = blockIdx.x * 256 + threadIdx.x;          // o = tap*2048 + co*64 + ci
    if (o >= 27 * 32 * 64) return;
    int ci = o & 63, co = (o >> 6) & 31, tap = o >> 11;
    wT[o] = (_Float16)w[ci * (32 * 27) + co * 27 + tap];
}

// ---- k0b: x (n,ci,id,ih,iw) f32 -> x16[n][id][ih][iwl 34][ci 64] f16 ----
// block per (n, id, ihg of 8 ih); thread = (iw = tid&31, ihq = tid>>5).
__global__ void x_to_f16t(const float* __restrict__ x, _Float16* __restrict__ x16) {
    const int tid = threadIdx.x;
    const unsigned b = blockIdx.x;                   // 256: id(5) | ihg(2) | n(1)
    const int id  = b & 31;
    const int ihg = (b >> 5) & 3;
    const int n   = b >> 7;
    const int iw  = tid & 31;
    const int ih  = ihg * 8 + (tid >> 5);

    const float* xr = x + (size_t)n * 2097152 + (id * 32 + ih) * 32 + iw;
    _Float16* drow = x16 + (size_t)n * X16_N_STRIDE + (id * 32 + ih) * X16_ROW;

    #pragma unroll
    for (int c0 = 0; c0 < 64; c0 += 16) {
        float f[16];
        #pragma unroll
        for (int j = 0; j < 16; ++j) f[j] = xr[(size_t)(c0 + j) * 32768];
        unsigned pk[8];
        #pragma unroll
        for (int j = 0; j < 8; ++j)
            pk[j] = __builtin_bit_cast(unsigned,
                        __builtin_amdgcn_cvt_pkrtz(f[2 * j], f[2 * j + 1]));
        _Float16* dst = drow + (iw + 1) * 64 + c0;
        ((uint4*)dst)[0] = make_uint4(pk[0], pk[1], pk[2], pk[3]);
        ((uint4*)dst)[1] = make_uint4(pk[4], pk[5], pk[6], pk[7]);
    }
    // zero halo: iwl = 0 and 33 for this block's 8 ih rows
    if (tid < 128) {
        const int side = tid >> 6;                   // 0 -> iwl 0, 1 -> iwl 33
        const int ihq2 = (tid >> 3) & 7;
        const int q    = tid & 7;
        _Float16* hz = x16 + (size_t)n * X16_N_STRIDE +
                       (id * 32 + ihg * 8 + ihq2) * X16_ROW + side * 33 * 64 + q * 8;
        ((uint4*)hz)[0] = make_uint4(0, 0, 0, 0);
    }
}

// ---- k1: bias over the 34 pure-bias planes per (n,co): od even + od=65 ----
#define BIAS_TOT4 (2*32*34*(PL/4))
__global__ void bias_planes(const float* __restrict__ bias, float* __restrict__ out) {
    const int tid = threadIdx.x;
    const unsigned base = blockIdx.x * 4096u;
    #pragma unroll
    for (int j = 0; j < 16; ++j) {
        unsigned idx = base + j * 256u + tid;
        if (idx >= BIAS_TOT4) continue;
        unsigned pl = idx / 1089u;
        unsigned slot = idx - pl * 1089u;
        unsigned e  = pl % 34u;
        unsigned nc = pl / 34u;
        unsigned od = (e < 33u) ? 2u * e : 65u;
        float v = bias[nc & 31u];
        float4* p = (float4*)(out + ((size_t)nc * DOUT + od) * PL);
        p[slot] = make_float4(v, v, v, v);
    }
}

// ---- k2: MFMA conv, B-frags straight from x16, split-K wave pairs ----
// block = 4 waves: pair = wv>>1 (hp rows hp0, hp0+1), kseg = wv&1 (ci half).
__global__ void __launch_bounds__(256, 2) convt_mfma(
    const _Float16* __restrict__ x16, const _Float16* __restrict__ wT,
    const float* __restrict__ bias, float* __restrict__ out)
{
    __shared__ float redu[2][2][16][64];             // 16384 B

    const int tid  = threadIdx.x;
    const int lane = tid & 63;
    const int wv   = tid >> 6;
    const int pair = wv >> 1;
    const int kseg = wv & 1;

    unsigned b = blockIdx.x;                         // 512: xcd(3) | dp(5) | hq(1)
    const unsigned xcd = b & 7u;
    const int n   = xcd & 1;
    const int dp  = (b >> 3) & 31;
    const int hq  = b >> 8;
    const int hpg = (int)(((xcd >> 1) << 1) | hq);   // 0..7
    const int hp0 = hpg * 4 + pair * 2;

    const int wp  = lane & 31;
    const int kh8 = (lane >> 5) * 8;

    // A lane ptr: wT[tap][co=lane&31][ci = kseg*32 + cc*16 + kh8 + j]
    const _Float16* wtl = wT + (lane & 31) * 64 + kseg * 32 + kh8;
    // B lane base: x16[n][id][ih][iwl = wp+2-kw][ci = kseg*32 + cc*16 + kh8 + j]
    const _Float16* xb = x16 + (size_t)n * X16_N_STRIDE + wp * 64 + kseg * 32 + kh8;

    floatx16 a0 = {}, a1 = {};

    if (dp >= 1 && dp <= 30 && hp0 >= 1 && hp0 <= 29) {
        // interior: branch-free, fully predictable
        #pragma unroll 3
        for (int t9 = 0; t9 < 9; ++t9) {
            const int kd = t9 / 3, kh = t9 % 3;
            const _Float16* bp0 = xb + ((dp + 1 - kd) * 32 + (hp0 + 1 - kh)) * X16_ROW;
            const _Float16* wt = wtl + t9 * 3 * 2048;
            #pragma unroll
            for (int kw = 0; kw < 3; ++kw) {
                const int off = (2 - kw) * 64;
                #pragma unroll
                for (int cc = 0; cc < 2; ++cc) {
                    uint4 au  = *(const uint4*)(wt + kw * 2048 + cc * 16);
                    uint4 bu0 = *(const uint4*)(bp0 + off + cc * 16);
                    uint4 bu1 = *(const uint4*)(bp0 + X16_ROW + off + cc * 16);
                    a0 = __builtin_amdgcn_mfma_f32_32x32x16_f16(
                        __builtin_bit_cast(half8, au), __builtin_bit_cast(half8, bu0),
                        a0, 0, 0, 0);
                    a1 = __builtin_amdgcn_mfma_f32_32x32x16_f16(
                        __builtin_bit_cast(half8, au), __builtin_bit_cast(half8, bu1),
                        a1, 0, 0, 0);
                }
            }
        }
    } else {
        // boundary: wave-uniform guards (skipped taps contribute zero)
        #pragma unroll 1
        for (int t9 = 0; t9 < 9; ++t9) {
            const int kd = t9 / 3, kh = t9 % 3;
            const int id = dp + 1 - kd;
            if ((unsigned)id >= 32u) continue;
            const int ih0 = hp0 + 1 - kh;
            const bool v0 = (unsigned)ih0 < 32u;
            const bool v1 = (unsigned)(ih0 + 1) < 32u;
            const _Float16* bp0 = xb + (id * 32 + ih0) * X16_ROW;
            const _Float16* wt = wtl + t9 * 3 * 2048;
            #pragma unroll
            for (int kw = 0; kw < 3; ++kw) {
                const int off = (2 - kw) * 64;
                #pragma unroll
                for (int cc = 0; cc < 2; ++cc) {
                    uint4 au = *(const uint4*)(wt + kw * 2048 + cc * 16);
                    if (v0) {
                        uint4 bu0 = *(const uint4*)(bp0 + off + cc * 16);
                        a0 = __builtin_amdgcn_mfma_f32_32x32x16_f16(
                            __builtin_bit_cast(half8, au), __builtin_bit_cast(half8, bu0),
                            a0, 0, 0, 0);
                    }
                    if (v1) {
                        uint4 bu1 = *(const uint4*)(bp0 + X16_ROW + off + cc * 16);
                        a1 = __builtin_amdgcn_mfma_f32_32x32x16_f16(
                            __builtin_bit_cast(half8, au), __builtin_bit_cast(half8, bu1),
                            a1, 0, 0, 0);
                    }
                }
            }
        }
    }

    // ---- split-K reduction: kseg1 -> LDS, kseg0 adds ----
    if (kseg == 1) {
        #pragma unroll
        for (int r = 0; r < 16; ++r) {
            redu[pair][0][r][lane] = a0[r];
            redu[pair][1][r][lane] = a1[r];
        }
    }
    __syncthreads();

    const int od = 2 * dp + 1;
    if (kseg == 0) {
        #pragma unroll
        for (int r = 0; r < 16; ++r) {
            a0[r] += redu[pair][0][r][lane];
            a1[r] += redu[pair][1][r][lane];
        }
        // conv rows: oh = 2hp+1 for hp0, hp0+1
        #pragma unroll
        for (int t = 0; t < 2; ++t) {
            const int oh = 2 * (hp0 + t) + 1;
            const floatx16& acc = t ? a1 : a0;
            #pragma unroll
            for (int r = 0; r < 16; ++r) {
                const int co = (r & 3) + 8 * (r >> 2) + 4 * (lane >> 5);
                const float bv = bias[co];
                float2* orow = (float2*)(out +
                    ((size_t)(n * 32 + co) * DOUT + od) * PL + oh * DOUT);
                orow[wp] = make_float2(bv, acc[r] + bv);
                if (wp == 31) orow[32] = make_float2(bv, bv);
            }
        }
    } else {
        // bias rows: oh = 2hp (even) for hp0, hp0+1; plus oh 64,65 tails
        const bool tails = (hpg == 7) && (pair == 1);
        #pragma unroll
        for (int r = 0; r < 16; ++r) {
            const int co = (r & 3) + 8 * (r >> 2) + 4 * (lane >> 5);
            const float bv = bias[co];
            float* pbase = out + ((size_t)(n * 32 + co) * DOUT + od) * PL;
            #pragma unroll
            for (int t = 0; t < 2; ++t) {
                float2* erow = (float2*)(pbase + (2 * (hp0 + t)) * DOUT);
                erow[wp] = make_float2(bv, bv);
                if (wp == 31) erow[32] = make_float2(bv, bv);
            }
            if (tails) {
                float2* t0 = (float2*)(pbase + 64 * DOUT);
                float2* t1 = (float2*)(pbase + 65 * DOUT);
                t0[wp] = make_float2(bv, bv);
                t1[wp] = make_float2(bv, bv);
                if (wp == 31) { t0[32] = make_float2(bv, bv); t1[32] = make_float2(bv, bv); }
            }
        }
    }
}

extern "C" void kernel_launch(void* const* d_in, const int* in_sizes, int n_in,
                              void* d_out, int out_size, void* d_ws, size_t ws_size,
                              hipStream_t stream) {
    const float* x    = (const float*)d_in[0];
    const float* wgt  = (const float*)d_in[1];
    const float* bias = (const float*)d_in[2];
    float* out = (float*)d_out;
    _Float16* wT  = (_Float16*)d_ws;                 // 110,592 B
    _Float16* x16 = (_Float16*)((char*)d_ws + X16_OFF);  // 8,912,896 B

    w_transpose<<<216, 256, 0, stream>>>(wgt, wT);
    x_to_f16t<<<256, 256, 0, stream>>>(x, x16);
    bias_planes<<<(BIAS_TOT4 + 4095) / 4096, 256, 0, stream>>>(bias, out);
    convt_mfma<<<512, 256, 0, stream>>>(x16, wT, bias, out);
}